// Round 7
// baseline (2438.862 us; speedup 1.0000x reference)
//
#include <hip/hip_runtime.h>
#include <hip/hip_bf16.h>

typedef __hip_bfloat16 bf16;
typedef __attribute__((ext_vector_type(4))) unsigned int u32x4;
typedef __attribute__((ext_vector_type(4))) float f32x4;
typedef __attribute__((ext_vector_type(8))) short bf16x8;
#define DEV __device__ __forceinline__

// ---------------- problem constants ----------------
// N=16, C=64, H=W=160, S=25600, expanded channels 192, windows {1,3,5}

// fp32 scratch layout (offsets in floats)
constexpr int FO_Q     = 0;         // raw softmax logits, per-window concat (1239104)
constexpr int FO_SMAP  = 1239104;   // sigmoid spatial gate (1239104)
constexpr int FO_XM    = 2478208;   // per-(b,c') channel sums (560*64)
constexpr int FO_T     = 2514048;   // per-(b,c') q-weighted sums (560*64)
constexpr int FO_SIGA  = 2549888;   // per-(b,c') channel gate sigmoid(zn) (560*64)
constexpr int FO_G     = 2585728;   // per-(b,c') spatial-branch weights (560*64)
constexpr int FO_BM    = 2621568;   // per-b logit max (560)
constexpr int FO_BINV  = 2622128;   // per-b 1/sum(exp) (560)
constexpr int FO_GB    = 2622688;   // per-b spatial bias term (560)
constexpr int FO_EXPT  = 2623248;   // exp_w transposed [c*192+o] (12288)
constexpr int FO_EXPB  = 2635536;   // exp_b fp32 (192)
constexpr int FO_WBIGT = 2635728;   // combined final weight [k*64+f], k<256 (16384)
constexpr int FO_BCOMB = 2652112;   // combined final bias (64)
constexpr int FO_WFRAG = 2652176;   // bf16 A-fragment-ordered weights (16384 bf16 = 8192 f)
constexpr int FB_SIZE  = 2660368;

__device__ unsigned short g_ex2_u[104857600]; // ex2 [n][25600s][256ch] bf16 (single layout)
__device__ float          g_fb[FB_SIZE];

template<int WIN> struct WP;
template<> struct WP<1> { static constexpr int WI=0, SH=160, KH=160, K=25600, P=1,  B=16,  QOFF=0,      BOFF=0;   };
template<> struct WP<3> { static constexpr int WI=1, SH=53,  KH=54,  K=2916,  P=9,  B=144, QOFF=409600, BOFF=16;  };
template<> struct WP<5> { static constexpr int WI=2, SH=32,  KH=32,  K=1024,  P=25, B=400, QOFF=829504, BOFF=160; };

// psa-space walk helpers (used by pass kernels)
template<int WIN> DEV void decomp(int f, int& c, int& kidx, int& p) {
  constexpr int P = WP<WIN>::P, K = WP<WIN>::K;
  int m;
  if constexpr (P == 1) { p = 0; m = f; }
  else { m = f / P; p = f - m * P; }
  c = m / K; kidx = m - c * K;
}

template<int WIN> DEV void stepK(int& c, int& kidx, int& p) {  // f += K
  constexpr int K = WP<WIN>::K, P = WP<WIN>::P;
  if constexpr (P == 1) { kidx += K; }
  else {
    constexpr int KMP = K % P, KDP = K / P;
    if constexpr (KMP == 0) { kidx += KDP; }
    else { p += KMP; if (p >= P) { p -= P; kidx += KDP + 1; } else kidx += KDP; }
  }
  if (kidx >= K) { kidx -= K; ++c; }
}

template<int WIN> DEV int pix(int kidx, int p) {
  constexpr int KH = WP<WIN>::KH, SH = WP<WIN>::SH;
  if constexpr (WIN == 1) return kidx;
  int ki = kidx / KH, kj = kidx - ki * KH;
  int ph = p / WIN,  pw = p - ph * WIN;
  return (ph * SH + ki) * 160 + pw * SH + kj;
}

DEV unsigned short bfbits(float f) {
  bf16 b = __float2bfloat16(f);
  unsigned short u;
  __builtin_memcpy(&u, &b, 2);
  return u;
}

DEV float bf2f(unsigned short u) {
  bf16 b;
  __builtin_memcpy(&b, &u, 2);
  return __bfloat162float(b);
}

DEV void store8bf(bf16* p, const unsigned short* ob) {
  u32x4 v = { (unsigned)ob[0] | ((unsigned)ob[1] << 16),
              (unsigned)ob[2] | ((unsigned)ob[3] << 16),
              (unsigned)ob[4] | ((unsigned)ob[5] << 16),
              (unsigned)ob[6] | ((unsigned)ob[7] << 16) };
  *(u32x4*)p = v;
}

DEV bf16x8 as_bf16x8(u32x4 v) {
  union { u32x4 u; bf16x8 b; } x; x.u = v; return x.b;
}

// Butterfly reduce: part[c] summed across the 64 lanes of a wave; ends with
// lane l holding the total for channel bitrev6(l); one coalesced atomic.
DEV void wave_reduce64_atomic(float* dst, float (&part)[64], int lane) {
#pragma unroll
  for (int s = 0; s < 6; ++s) {
    const int m = 1 << s, half = 32 >> s;
#pragma unroll
    for (int i = 0; i < half; ++i) {
      float lo = part[i], hi = part[i + half];
      float keep = (lane & m) ? hi : lo;
      float sv   = (lane & m) ? lo : hi;
      float recv = __shfl_xor(sv, m, 64);
      part[i] = keep + recv;
    }
  }
  int chn = (int)(__brev((unsigned)lane) >> 26);
  atomicAdd(dst + chn, part[0]);
}

// ---------------- k_prep ----------------
__global__ __launch_bounds__(256)
void k_prep(const float* __restrict__ exp_w, const float* __restrict__ exp_b,
            const float* __restrict__ res_w, const float* __restrict__ res_b,
            const float* __restrict__ fus_w, const float* __restrict__ fus_b) {
  float* fb = g_fb;
  int gt = blockIdx.x * 256 + threadIdx.x;
  if (gt < 12288) {                       // Wcomb[f][oc] = sum_o fus[f][o]*res[o][oc]
    int oc = gt % 192, f = gt / 192;
    float a = 0.f;
    for (int o = 0; o < 64; ++o)
      a += fus_w[f*64+o] * res_w[o*192+oc];
    fb[FO_WBIGT + oc*64 + f] = a;
  } else if (gt < 16384) {                // rows 192..255: fus_w
    int t2 = gt - 12288; int o = t2 % 64, f = t2 / 64;
    fb[FO_WBIGT + (192+o)*64 + f] = fus_w[f*64+o];
  } else if (gt < 16448) {                // bcomb
    int f = gt - 16384;
    float a = fus_b[f];
    for (int o = 0; o < 64; ++o)
      a += fus_w[f*64+o] * res_b[o];
    fb[FO_BCOMB + f] = a;
  } else if (gt < 28736) {                // expT[c*192+o] = exp_w[o][c]
    int t3 = gt - 16448; int o = t3 % 192, c = t3 / 192;
    fb[FO_EXPT + c*192 + o] = exp_w[o*64+c];
  } else if (gt < 28928) {
    int o = gt - 28736;
    fb[FO_EXPB + o] = exp_b[o];
  } else if (gt < 28928 + 71680) {        // zero xm and t (contiguous)
    fb[FO_XM + gt - 28928] = 0.f;
  }
}

// ---------------- k_prep2: bake bf16 A-fragments for the final MFMA ----------
__global__ __launch_bounds__(256)
void k_prep2() {
  float* fb = g_fb;
  bf16* wf = (bf16*)(fb + FO_WFRAG);
  int t = blockIdx.x * 256 + threadIdx.x;     // 0..16383
  int j  = t & 7;
  int l  = (t >> 3) & 63;
  int ks = (t >> 9) & 7;
  int wv = t >> 12;
  int k = ks*32 + (l >> 4)*8 + j;
  int o = wv*16 + (l & 15);
  wf[t] = __float2bfloat16(fb[FO_WBIGT + k*64 + o]);
}

// ---------------- k_ex: ex2 = conv1x1(x, exp_w, exp_b) + x passthrough ------
// 4 waves x 48 conv outputs each (o0 = wv*48) + 16 x-channels each.
__global__ __launch_bounds__(256)
void k_ex(const float* __restrict__ x) {
  const float* fb = g_fb;
  bf16* ex2 = (bf16*)g_ex2_u;
  __shared__ float xs[64*64];
  int blk = blockIdx.x; int n = blk / 400; int s0 = (blk % 400) * 64;
  int tid = threadIdx.x;
  for (int e = tid; e < 4096; e += 256) {
    int c = e >> 6, px = e & 63;
    xs[e] = x[(n*64 + c)*25600 + s0 + px];
  }
  __syncthreads();
  int px = tid & 63;
  int wv = tid >> 6;
  int o0 = __builtin_amdgcn_readfirstlane(wv * 48);
  bf16* e2row = ex2 + (size_t)(n*25600 + s0 + px)*256;
  float acc[48];
#pragma unroll
  for (int j = 0; j < 48; ++j) acc[j] = fb[FO_EXPB + o0 + j];
  const float* wT = fb + FO_EXPT;
  for (int c = 0; c < 64; ++c) {
    float xv = xs[(c << 6) + px];
    const float* wr = wT + c*192 + o0;
#pragma unroll
    for (int j = 0; j < 48; ++j) acc[j] += wr[j] * xv;
  }
  unsigned short ob[8];
#pragma unroll
  for (int r = 0; r < 6; ++r) {
#pragma unroll
    for (int i = 0; i < 8; ++i) ob[i] = bfbits(acc[r*8 + i]);
    store8bf(e2row + o0 + r*8, ob);
  }
  // x passthrough: channels 192 + wv*16 .. +16
#pragma unroll
  for (int r = 0; r < 2; ++r) {
#pragma unroll
    for (int i = 0; i < 8; ++i)
      ob[i] = bfbits(xs[(wv*16 + r*8 + i)*64 + px]);
    store8bf(e2row + 192 + wv*16 + r*8, ob);
  }
}

// ---------------- k_p1all: fused logit + xm, barrier-free, all windows ------
// Each lane owns one sp and walks all 64 psa-channels (all reads from ex2).
template<int WIN, int CH, int CHUNK, int ITERS>
DEV void p1_body(int idx, const float* __restrict__ chq_w, float wqb) {
  using W = WP<WIN>;
  constexpr int K = W::K, P = W::P, CK = 64*K, WI = W::WI, QOFF = W::QOFF,
                BOFF = W::BOFF;
  float* fb = g_fb;
  const bf16* ex2 = (const bf16*)g_ex2_u;
  int bi = idx / CH, ch = idx - bi*CH;
  int n = bi / P, bl = bi - n*P; int bg = BOFF + bi;
  int base = ch*CHUNK;
  int send = (base + CHUNK < K) ? base + CHUNK : K;
  const bf16* e2n = ex2 + (size_t)n*25600*256 + WI*64;
  float* qout = fb + FO_Q + QOFF + (size_t)bi*K;
  int tid = threadIdx.x, lane = tid & 63;
  float wq[64];
#pragma unroll
  for (int j = 0; j < 64; ++j) wq[j] = chq_w[j];
  float part[64];
#pragma unroll
  for (int j = 0; j < 64; ++j) part[j] = 0.f;
  for (int it = 0; it < ITERS; ++it) {
    int sp = base + it*256 + tid;
    if (sp < send) {
      float dot = 0.f;
      if constexpr (WIN == 1) {
        const u32x4* e2 = (const u32x4*)(e2n + (size_t)sp*256);
#pragma unroll
        for (int r = 0; r < 8; ++r) {
          u32x4 v = e2[r];
#pragma unroll
          for (int i = 0; i < 4; ++i) {
            int c = r*8 + 2*i;
            float lo = bf2f((unsigned short)(v[i] & 0xffffu));
            float hi = bf2f((unsigned short)(v[i] >> 16));
            part[c]   += lo;  dot += wq[c]   * lo;
            part[c+1] += hi;  dot += wq[c+1] * hi;
          }
        }
      } else {
        int f = bl*CK + sp;
        int c, kidx, p; decomp<WIN>(f, c, kidx, p);
#pragma unroll
        for (int j = 0; j < 64; ++j) {
          float v = bf2f(((const unsigned short*)e2n)[(size_t)pix<WIN>(kidx, p)*256 + c]);
          part[j] += v;
          dot += wq[j] * v;
          stepK<WIN>(c, kidx, p);
        }
      }
      qout[sp] = dot + wqb;
    }
  }
  wave_reduce64_atomic(fb + FO_XM + bg*64, part, lane);
}

__global__ __launch_bounds__(256, 2)
void k_p1all(const float* __restrict__ chq_w, const float* __restrict__ chq_b) {
  float wqb = chq_b[0];
  int blk = blockIdx.x;
  if (blk < 400)      p1_body<1,25,1024,4>(blk,       chq_w, wqb);
  else if (blk < 832) p1_body<3, 3, 972,4>(blk - 400, chq_w, wqb);
  else                p1_body<5, 2, 512,2>(blk - 832, chq_w, wqb);
}

// ---------------- k_bstats: per-b softmax stats + spatial branch ----------------
__global__ __launch_bounds__(256)
void k_bstats(const float* __restrict__ spq_w, const float* __restrict__ spq_b,
              const float* __restrict__ spv_w, const float* __restrict__ spv_b) {
  float* fb = g_fb;
  __shared__ float red[256]; __shared__ float sqs[32]; __shared__ float swq[32];
  int bg = blockIdx.x, tid = threadIdx.x;
  int Kk, qo, bi;
  if (bg < 16)       { Kk = 25600; qo = 0;      bi = bg;       }
  else if (bg < 160) { Kk = 2916;  qo = 409600; bi = bg - 16;  }
  else               { Kk = 1024;  qo = 829504; bi = bg - 160; }
  const float* lg = fb + FO_Q + qo + (size_t)bi*Kk;
  float m = -1e30f;
  for (int s = tid; s < Kk; s += 256) m = fmaxf(m, lg[s]);
  red[tid] = m; __syncthreads();
  for (int st = 128; st; st >>= 1) { if (tid < st) red[tid] = fmaxf(red[tid], red[tid+st]); __syncthreads(); }
  float M = red[0]; __syncthreads();
  float ss = 0.f;
  for (int s = tid; s < Kk; s += 256) ss += __expf(lg[s] - M);
  red[tid] = ss; __syncthreads();
  for (int st = 128; st; st >>= 1) { if (tid < st) red[tid] += red[tid+st]; __syncthreads(); }
  if (tid == 0) { fb[FO_BM + bg] = M; fb[FO_BINV + bg] = 1.f / red[0]; }
  const float* xm_b = fb + FO_XM + bg*64;
  float rK = 1.f / (float)Kk;
  if (tid < 32) {
    float a = spq_b[tid];
    for (int c = 0; c < 64; ++c)
      a += spq_w[tid*64 + c] * (xm_b[c] * rK);
    sqs[tid] = a;
  }
  __syncthreads();
  if (tid == 0) {
    float mx = -1e30f;
    for (int o = 0; o < 32; ++o) mx = fmaxf(mx, sqs[o]);
    float z = 0.f;
    for (int o = 0; o < 32; ++o) { float e = __expf(sqs[o] - mx); swq[o] = e; z += e; }
    float rz = 1.f / z;
    for (int o = 0; o < 32; ++o) swq[o] *= rz;
  }
  __syncthreads();
  if (tid < 64) {
    float a = 0.f;
    for (int o = 0; o < 32; ++o) a += swq[o] * spv_w[o*64 + tid];
    fb[FO_G + bg*64 + tid] = a;
  }
  if (tid == 64) {
    float gb = 0.f;
    for (int o = 0; o < 32; ++o) gb += swq[o] * spv_b[o];
    fb[FO_GB + bg] = gb;
  }
}

// ---------------- k_p2all: fused t + smap, barrier-free, all windows --------
template<int WIN, int CH, int CHUNK, int ITERS>
DEV void p2_body(int idx) {
  using W = WP<WIN>;
  constexpr int K = W::K, P = W::P, CK = 64*K, WI = W::WI, QOFF = W::QOFF,
                BOFF = W::BOFF;
  float* fb = g_fb;
  const bf16* ex2 = (const bf16*)g_ex2_u;
  int bi = idx / CH, ch = idx - bi*CH;
  int n = bi / P, bl = bi - n*P; int bg = BOFF + bi;
  int base = ch*CHUNK;
  int send = (base + CHUNK < K) ? base + CHUNK : K;
  const bf16* e2n = ex2 + (size_t)n*25600*256 + WI*64;
  const float* qin = fb + FO_Q + QOFF + (size_t)bi*K;
  float* so = fb + FO_SMAP + QOFF + (size_t)bi*K;
  float M = fb[FO_BM + bg], inv = fb[FO_BINV + bg];
  float gbs = fb[FO_GB + bg];
  int tid = threadIdx.x, lane = tid & 63;
  float gs[64];
#pragma unroll
  for (int j = 0; j < 64; ++j) gs[j] = fb[FO_G + bg*64 + j];
  float part[64];
#pragma unroll
  for (int j = 0; j < 64; ++j) part[j] = 0.f;
  for (int it = 0; it < ITERS; ++it) {
    int sp = base + it*256 + tid;
    if (sp < send) {
      float qv = __expf(qin[sp] - M) * inv;
      float dot = 0.f;
      if constexpr (WIN == 1) {
        const u32x4* e2 = (const u32x4*)(e2n + (size_t)sp*256);
#pragma unroll
        for (int r = 0; r < 8; ++r) {
          u32x4 v = e2[r];
#pragma unroll
          for (int i = 0; i < 4; ++i) {
            int c = r*8 + 2*i;
            float lo = bf2f((unsigned short)(v[i] & 0xffffu));
            float hi = bf2f((unsigned short)(v[i] >> 16));
            part[c]   += qv * lo;  dot += gs[c]   * lo;
            part[c+1] += qv * hi;  dot += gs[c+1] * hi;
          }
        }
      } else {
        int f = bl*CK + sp;
        int c, kidx, p; decomp<WIN>(f, c, kidx, p);
#pragma unroll
        for (int j = 0; j < 64; ++j) {
          float v = bf2f(((const unsigned short*)e2n)[(size_t)pix<WIN>(kidx, p)*256 + c]);
          part[j] += qv * v;
          dot += gs[j] * v;
          stepK<WIN>(c, kidx, p);
        }
      }
      so[sp] = 1.f / (1.f + __expf(-(dot + gbs)));
    }
  }
  wave_reduce64_atomic(fb + FO_T + bg*64, part, lane);
}

__global__ __launch_bounds__(256, 2)
void k_p2all() {
  int blk = blockIdx.x;
  if (blk < 400)      p2_body<1,25,1024,4>(blk);
  else if (blk < 832) p2_body<3, 3, 972,4>(blk - 400);
  else                p2_body<5, 2, 512,2>(blk - 832);
}

// ---------------- k_zln: wz -> z -> LayerNorm -> sigA ----------------
__global__ __launch_bounds__(64)
void k_zln(const float* __restrict__ chv_w, const float* __restrict__ chv_b,
           const float* __restrict__ chz_w, const float* __restrict__ chz_b,
           const float* __restrict__ ln_g,  const float* __restrict__ ln_b) {
  float* fb = g_fb;
  __shared__ float wzs[32]; __shared__ float zsh[64]; __shared__ float mom[2];
  int bg = blockIdx.x, tid = threadIdx.x;
  const float* t_b = fb + FO_T + bg*64;
  if (tid < 32) {
    float a = chv_b[tid];
    for (int c = 0; c < 64; ++c)
      a += chv_w[tid*64 + c] * t_b[c];
    wzs[tid] = a;
  }
  __syncthreads();
  float zv = chz_b[tid];
  for (int o = 0; o < 32; ++o)
    zv += chz_w[tid*32 + o] * wzs[o];
  zsh[tid] = zv;
  __syncthreads();
  if (tid == 0) {
    float mu = 0.f;
    for (int j = 0; j < 64; ++j) mu += zsh[j];
    mu *= (1.f/64.f);
    float m2 = 0.f;
    for (int j = 0; j < 64; ++j) { float d = zsh[j] - mu; m2 += d*d; }
    m2 *= (1.f/64.f);
    mom[0] = mu; mom[1] = rsqrtf(m2 + 1e-5f);
  }
  __syncthreads();
  float zn = (zv - mom[0]) * mom[1] * ln_g[tid] + ln_b[tid];
  fb[FO_SIGA + bg*64 + tid] = 1.f / (1.f + __expf(-zn));
}

// ---------------- k_final: gates -> extT (bf16, swizzled LDS) -> MFMA conv ----
template<int WIN> DEV void gate_rows3(int n, int s, int h, int w, int px,
                                      const float* __restrict__ fb,
                                      const bf16* __restrict__ e2row,
                                      bf16* extT) {
  using W = WP<WIN>;
  constexpr int SH = W::SH, KH = W::KH, K = W::K, P = W::P, WI = W::WI,
                QOFF = W::QOFF, BOFF = W::BOFF;
  const float* smap = fb + FO_SMAP + QOFF + (size_t)(n*P)*K;
  const float* sg   = fb + FO_SIGA + (size_t)(BOFF + n*P)*64;
  const u32x4* src = (const u32x4*)(e2row + WI*64);
  u32x4 vv[8];
#pragma unroll
  for (int r = 0; r < 8; ++r) vv[r] = src[r];
  int swz = (px & 7) << 3;
  unsigned short ob[8];
  if constexpr (WIN == 1) {
    float sm = smap[s];
#pragma unroll
    for (int r = 0; r < 8; ++r) {
#pragma unroll
      for (int i = 0; i < 4; ++i) {
        int c = r*8 + 2*i;
        float lo = bf2f((unsigned short)(vv[r][i] & 0xffffu));
        float hi = bf2f((unsigned short)(vv[r][i] >> 16));
        ob[2*i]   = bfbits(lo * (1.f + sg[c]   + sm));
        ob[2*i+1] = bfbits(hi * (1.f + sg[c+1] + sm));
      }
      store8bf(&extT[px*256 + ((WI*64 + r*8) ^ swz)], ob);
    }
  } else {
    int phmin = (h >= KH) ? (h - KH)/SH + 1 : 0;
    int phmax = (WIN-1 < h/SH) ? WIN-1 : h/SH;
    int pwmin = (w >= KH) ? (w - KH)/SH + 1 : 0;
    int pwmax = (WIN-1 < w/SH) ? WIN-1 : w/SH;
    int cf[4]; int s0s[4]; int np = 0;
    for (int ph = phmin; ph <= phmax; ++ph)
      for (int pw = pwmin; pw <= pwmax; ++pw) {
        int ki = h - ph*SH, kj = w - pw*SH;
        unsigned base0 = (unsigned)((ki*KH + kj)*P + ph*WIN + pw);
        unsigned q = base0 / (unsigned)K;
        cf[np] = (int)q; s0s[np] = (int)(base0 - q*(unsigned)K); ++np;
      }
    float rc = 1.f / (float)np;
    int hi4[4]; float smv[4];
#pragma unroll
    for (int t = 0; t < 4; ++t)
      if (t < np) { hi4[t] = cf[t] >> 6; smv[t] = smap[hi4[t]*K + s0s[t]]; }
#pragma unroll
    for (int r = 0; r < 8; ++r) {
#pragma unroll
      for (int cc = 0; cc < 8; ++cc) {
        float gsum = 0.f;
#pragma unroll
        for (int t = 0; t < 4; ++t) {
          if (t < np) {
            int v = cf[t];
            int h2 = v >> 6;
            if (h2 != hi4[t]) { hi4[t] = h2; smv[t] = smap[h2*K + s0s[t]]; }
            gsum += sg[v] + smv[t];
            cf[t] = v + P;
          }
        }
        unsigned wd = vv[r][cc >> 1];
        unsigned short eb = (cc & 1) ? (unsigned short)(wd >> 16)
                                     : (unsigned short)(wd & 0xffffu);
        ob[cc] = bfbits(bf2f(eb) * (1.f + gsum * rc));
      }
      store8bf(&extT[px*256 + ((WI*64 + r*8) ^ swz)], ob);
    }
  }
}

__global__ __launch_bounds__(256)
void k_final(float* __restrict__ out) {
  const float* fb = g_fb;
  const bf16* ex2 = (const bf16*)g_ex2_u;
  __shared__ __align__(16) bf16 extT[64*256];   // [px][k] swizzled, 32 KB
  int blk = blockIdx.x; int n = blk / 400; int s0 = (blk % 400) * 64;
  int tid = threadIdx.x;
  int rg = tid >> 6; int px = tid & 63;
  int s = s0 + px; int h = s / 160; int w = s - h*160;
  const bf16* e2row = ex2 + (size_t)(n*25600 + s)*256;
  if (rg == 3) {
    // x channels 192..255: straight copy (already bf16 in ex2)
    const u32x4* src = (const u32x4*)(e2row + 192);
    int swz = (px & 7) << 3;
#pragma unroll
    for (int r = 0; r < 8; ++r)
      *(u32x4*)&extT[px*256 + ((192 + r*8) ^ swz)] = src[r];
  } else if (rg == 0) gate_rows3<1>(n, s, h, w, px, fb, e2row, extT);
  else if (rg == 1)   gate_rows3<3>(n, s, h, w, px, fb, e2row, extT);
  else                gate_rows3<5>(n, s, h, w, px, fb, e2row, extT);
  __syncthreads();

  // ---- MFMA: out[o][px] = sum_k W[k][o] * extT[px][k], K=256 ----
  int wv = tid >> 6; int l = tid & 63;
  int lx = l & 15, g = l >> 4;
  const u32x4* wfA = (const u32x4*)(fb + FO_WFRAG);
  u32x4 af[8];
#pragma unroll
  for (int ks = 0; ks < 8; ++ks) af[ks] = wfA[(wv*8 + ks)*64 + l];
  f32x4 acc[4];
#pragma unroll
  for (int pt = 0; pt < 4; ++pt) acc[pt] = f32x4{0.f, 0.f, 0.f, 0.f};
#pragma unroll
  for (int ks = 0; ks < 8; ++ks) {
#pragma unroll
    for (int pt = 0; pt < 4; ++pt) {
      int pxx = pt*16 + lx;
      const u32x4* bp = (const u32x4*)&extT[pxx*256 + ((ks*32 + g*8) ^ ((pxx & 7) << 3))];
      acc[pt] = __builtin_amdgcn_mfma_f32_16x16x32_bf16(
                  as_bf16x8(af[ks]), as_bf16x8(*bp), acc[pt], 0, 0, 0);
    }
  }
  float bia[4];
#pragma unroll
  for (int r = 0; r < 4; ++r) bia[r] = fb[FO_BCOMB + wv*16 + g*4 + r];
#pragma unroll
  for (int pt = 0; pt < 4; ++pt) {
#pragma unroll
    for (int r = 0; r < 4; ++r)
      out[(size_t)(n*64 + wv*16 + g*4 + r)*25600 + s0 + pt*16 + lx] = acc[pt][r] + bia[r];
  }
}

// ---------------- launch ----------------
extern "C" void kernel_launch(void* const* d_in, const int* in_sizes, int n_in,
                              void* d_out, int out_size, void* d_ws, size_t ws_size,
                              hipStream_t stream) {
  const float* x     = (const float*)d_in[0];
  const float* exp_w = (const float*)d_in[1];
  const float* exp_b = (const float*)d_in[2];
  const float* res_w = (const float*)d_in[3];
  const float* res_b = (const float*)d_in[4];
  const float* fus_w = (const float*)d_in[5];
  const float* fus_b = (const float*)d_in[6];
  const float* chv_w = (const float*)d_in[7];
  const float* chv_b = (const float*)d_in[8];
  const float* chq_w = (const float*)d_in[9];
  const float* chq_b = (const float*)d_in[10];
  const float* chz_w = (const float*)d_in[11];
  const float* chz_b = (const float*)d_in[12];
  const float* ln_g  = (const float*)d_in[13];
  const float* ln_b  = (const float*)d_in[14];
  const float* spv_w = (const float*)d_in[15];
  const float* spv_b = (const float*)d_in[16];
  const float* spq_w = (const float*)d_in[17];
  const float* spq_b = (const float*)d_in[18];
  float* out = (float*)d_out;

  k_prep<<<393, 256, 0, stream>>>(exp_w, exp_b, res_w, res_b, fus_w, fus_b);
  k_prep2<<<64, 256, 0, stream>>>();
  k_ex<<<6400, 256, 0, stream>>>(x);

  k_p1all<<<1632, 256, 0, stream>>>(chq_w, chq_b);

  k_bstats<<<560, 256, 0, stream>>>(spq_w, spq_b, spv_w, spv_b);

  k_p2all<<<1632, 256, 0, stream>>>();

  k_zln<<<560, 64, 0, stream>>>(chv_w, chv_b, chz_w, chz_b, ln_g, ln_b);

  k_final<<<6400, 256, 0, stream>>>(out);
}

// Round 8
// 924.459 us; speedup vs baseline: 2.6381x; 2.6381x over previous
//
#include <hip/hip_runtime.h>
#include <hip/hip_bf16.h>

typedef __hip_bfloat16 bf16;
typedef __attribute__((ext_vector_type(4))) unsigned int u32x4;
typedef __attribute__((ext_vector_type(4))) float f32x4;
typedef __attribute__((ext_vector_type(8))) short bf16x8;
#define DEV __device__ __forceinline__

// ---------------- problem constants ----------------
// N=16, C=64, H=W=160, S=25600, expanded channels 192, windows {1,3,5}

// fp32 scratch layout (offsets in floats)
constexpr int FO_Q     = 0;         // raw softmax logits, per-window concat (1239104)
constexpr int FO_SMAP  = 1239104;   // sigmoid spatial gate (1239104)
constexpr int FO_XM    = 2478208;   // per-(b,c') channel sums (560*64)
constexpr int FO_T     = 2514048;   // per-(b,c') q-weighted sums (560*64)
constexpr int FO_SIGA  = 2549888;   // per-(b,c') channel gate sigmoid(zn) (560*64)
constexpr int FO_G     = 2585728;   // per-(b,c') spatial-branch weights (560*64)
constexpr int FO_BM    = 2621568;   // per-b logit max (560)
constexpr int FO_BINV  = 2622128;   // per-b 1/sum(exp) (560)
constexpr int FO_GB    = 2622688;   // per-b spatial bias term (560)
constexpr int FO_EXPT  = 2623248;   // exp_w transposed [c*192+o] (12288)
constexpr int FO_EXPB  = 2635536;   // exp_b fp32 (192)
constexpr int FO_WBIGT = 2635728;   // combined final weight [k*64+f], k<256 (16384)
constexpr int FO_BCOMB = 2652112;   // combined final bias (64)
constexpr int FO_WFRAG = 2652176;   // bf16 A-fragment-ordered weights (16384 bf16 = 8192 f)
constexpr int FB_SIZE  = 2660368;

__device__ unsigned short g_ex_u[52428800];   // ex  [n][128ch][25600s] bf16, orig ch 64..191 (win3/5 passes)
__device__ unsigned short g_ex2_u[104857600]; // ex2 [n][25600s][256ch] bf16 (win1 passes + k_final)
__device__ float          g_fb[FB_SIZE];

template<int WIN> struct WP;
template<> struct WP<1> { static constexpr int WI=0, SH=160, KH=160, K=25600, P=1,  B=16,  QOFF=0,      BOFF=0,   EXO=0;  };
template<> struct WP<3> { static constexpr int WI=1, SH=53,  KH=54,  K=2916,  P=9,  B=144, QOFF=409600, BOFF=16,  EXO=0;  };
template<> struct WP<5> { static constexpr int WI=2, SH=32,  KH=32,  K=1024,  P=25, B=400, QOFF=829504, BOFF=160, EXO=64; };

// psa-space walk helpers (used by pass kernels)
template<int WIN> DEV void decomp(int f, int& c, int& kidx, int& p) {
  constexpr int P = WP<WIN>::P, K = WP<WIN>::K;
  int m;
  if constexpr (P == 1) { p = 0; m = f; }
  else { m = f / P; p = f - m * P; }
  c = m / K; kidx = m - c * K;
}

template<int WIN> DEV void stepK(int& c, int& kidx, int& p) {  // f += K
  constexpr int K = WP<WIN>::K, P = WP<WIN>::P;
  if constexpr (P == 1) { kidx += K; }
  else {
    constexpr int KMP = K % P, KDP = K / P;
    if constexpr (KMP == 0) { kidx += KDP; }
    else { p += KMP; if (p >= P) { p -= P; kidx += KDP + 1; } else kidx += KDP; }
  }
  if (kidx >= K) { kidx -= K; ++c; }
}

template<int WIN> DEV int pix(int kidx, int p) {
  constexpr int KH = WP<WIN>::KH, SH = WP<WIN>::SH;
  if constexpr (WIN == 1) return kidx;
  int ki = kidx / KH, kj = kidx - ki * KH;
  int ph = p / WIN,  pw = p - ph * WIN;
  return (ph * SH + ki) * 160 + pw * SH + kj;
}

DEV unsigned short bfbits(float f) {
  bf16 b = __float2bfloat16(f);
  unsigned short u;
  __builtin_memcpy(&u, &b, 2);
  return u;
}

DEV float bf2f(unsigned short u) {
  bf16 b;
  __builtin_memcpy(&b, &u, 2);
  return __bfloat162float(b);
}

DEV void store8bf(bf16* p, const unsigned short* ob) {
  u32x4 v = { (unsigned)ob[0] | ((unsigned)ob[1] << 16),
              (unsigned)ob[2] | ((unsigned)ob[3] << 16),
              (unsigned)ob[4] | ((unsigned)ob[5] << 16),
              (unsigned)ob[6] | ((unsigned)ob[7] << 16) };
  *(u32x4*)p = v;
}

DEV bf16x8 as_bf16x8(u32x4 v) {
  union { u32x4 u; bf16x8 b; } x; x.u = v; return x.b;
}

// ---------------- k_prep ----------------
__global__ __launch_bounds__(256)
void k_prep(const float* __restrict__ exp_w, const float* __restrict__ exp_b,
            const float* __restrict__ res_w, const float* __restrict__ res_b,
            const float* __restrict__ fus_w, const float* __restrict__ fus_b) {
  float* fb = g_fb;
  int gt = blockIdx.x * 256 + threadIdx.x;
  if (gt < 12288) {                       // Wcomb[f][oc] = sum_o fus[f][o]*res[o][oc]
    int oc = gt % 192, f = gt / 192;
    float a = 0.f;
    for (int o = 0; o < 64; ++o)
      a += fus_w[f*64+o] * res_w[o*192+oc];
    fb[FO_WBIGT + oc*64 + f] = a;
  } else if (gt < 16384) {                // rows 192..255: fus_w
    int t2 = gt - 12288; int o = t2 % 64, f = t2 / 64;
    fb[FO_WBIGT + (192+o)*64 + f] = fus_w[f*64+o];
  } else if (gt < 16448) {                // bcomb
    int f = gt - 16384;
    float a = fus_b[f];
    for (int o = 0; o < 64; ++o)
      a += fus_w[f*64+o] * res_b[o];
    fb[FO_BCOMB + f] = a;
  } else if (gt < 28736) {                // expT[c*192+o] = exp_w[o][c]
    int t3 = gt - 16448; int o = t3 % 192, c = t3 / 192;
    fb[FO_EXPT + c*192 + o] = exp_w[o*64+c];
  } else if (gt < 28928) {
    int o = gt - 28736;
    fb[FO_EXPB + o] = exp_b[o];
  } else if (gt < 28928 + 71680) {        // zero xm and t (contiguous)
    fb[FO_XM + gt - 28928] = 0.f;
  }
}

// ---------------- k_prep2: bake bf16 A-fragments for the final MFMA ----------
__global__ __launch_bounds__(256)
void k_prep2() {
  float* fb = g_fb;
  bf16* wf = (bf16*)(fb + FO_WFRAG);
  int t = blockIdx.x * 256 + threadIdx.x;     // 0..16383
  int j  = t & 7;
  int l  = (t >> 3) & 63;
  int ks = (t >> 9) & 7;
  int wv = t >> 12;
  int k = ks*32 + (l >> 4)*8 + j;
  int o = wv*16 + (l & 15);
  wf[t] = __float2bfloat16(fb[FO_WBIGT + k*64 + o]);
}

// ---------------- k_ex: conv1x1 -> ex (ch 64..191) + ex2 (all 256) ----------
__global__ __launch_bounds__(256)
void k_ex(const float* __restrict__ x) {
  const float* fb = g_fb;
  bf16* ex  = (bf16*)g_ex_u;
  bf16* ex2 = (bf16*)g_ex2_u;
  __shared__ float xs[64*64];
  int blk = blockIdx.x; int n = blk / 400; int s0 = (blk % 400) * 64;
  int tid = threadIdx.x;
  for (int e = tid; e < 4096; e += 256) {
    int c = e >> 6, px = e & 63;
    xs[e] = x[(n*64 + c)*25600 + s0 + px];
  }
  __syncthreads();
  int px = tid & 63;
  int wv = tid >> 6;
  int o0 = __builtin_amdgcn_readfirstlane(wv * 48);
  bf16* e2row = ex2 + (size_t)(n*25600 + s0 + px)*256;
  float acc[48];
#pragma unroll
  for (int j = 0; j < 48; ++j) acc[j] = fb[FO_EXPB + o0 + j];
  const float* wT = fb + FO_EXPT;
  for (int c = 0; c < 64; ++c) {
    float xv = xs[(c << 6) + px];
    const float* wr = wT + c*192 + o0;
#pragma unroll
    for (int j = 0; j < 48; ++j) acc[j] += wr[j] * xv;
  }
  unsigned short ob[8];
#pragma unroll
  for (int r = 0; r < 6; ++r) {
#pragma unroll
    for (int i = 0; i < 8; ++i) ob[i] = bfbits(acc[r*8 + i]);
    store8bf(e2row + o0 + r*8, ob);
  }
  // x passthrough: ex2 channels 192 + wv*16 .. +16
#pragma unroll
  for (int r = 0; r < 2; ++r) {
#pragma unroll
    for (int i = 0; i < 8; ++i)
      ob[i] = bfbits(xs[(wv*16 + r*8 + i)*64 + px]);
    store8bf(e2row + 192 + wv*16 + r*8, ob);
  }
  // ex (channel-major) only for original channels 64..191
  bf16* exb = ex + (size_t)n*128*25600 + s0 + px;
#pragma unroll
  for (int j = 0; j < 48; ++j) {
    int chn = o0 + j;
    if (chn >= 64)
      exb[(size_t)(chn - 64)*25600] = __float2bfloat16(acc[j]);
  }
}

// ---------------- k_q1x: win1 q-logits + xm (streaming over ex2) ------------
__global__ __launch_bounds__(256)
void k_q1x(const float* __restrict__ chq_w, const float* __restrict__ chq_b) {
  __shared__ float wqs[64];
  __shared__ float red2[256];
  float* fb = g_fb;
  const bf16* ex2 = (const bf16*)g_ex2_u;
  int blk = blockIdx.x; int n = blk / 50; int sbase = (blk % 50) * 512;
  int tid = threadIdx.x;
  if (tid < 64) wqs[tid] = chq_w[tid];
  __syncthreads();
  float wqb = chq_b[0];
  // phase 1: q[sp] = wq . ex2[sp][0:64]
  for (int it = 0; it < 2; ++it) {
    int sp = sbase + it*256 + tid;
    const u32x4* e2 = (const u32x4*)(ex2 + (size_t)(n*25600 + sp)*256);
    float dot = 0.f;
#pragma unroll
    for (int r = 0; r < 8; ++r) {
      u32x4 v = e2[r];
#pragma unroll
      for (int i = 0; i < 4; ++i) {
        int c = r*8 + 2*i;
        dot += wqs[c]   * bf2f((unsigned short)(v[i] & 0xffffu));
        dot += wqs[c+1] * bf2f((unsigned short)(v[i] >> 16));
      }
    }
    fb[FO_Q + (size_t)n*25600 + sp] = dot + wqb;
  }
  // phase 2: xm[c] += column sums (vectorized: thread owns channel-octet)
  int oct = tid & 7, rb = tid >> 3;
  float p8[8];
#pragma unroll
  for (int e = 0; e < 8; ++e) p8[e] = 0.f;
  for (int it = 0; it < 16; ++it) {
    int row = sbase + rb + it*32;
    u32x4 v = *(const u32x4*)(ex2 + (size_t)(n*25600 + row)*256 + oct*8);
#pragma unroll
    for (int i = 0; i < 4; ++i) {
      p8[2*i]   += bf2f((unsigned short)(v[i] & 0xffffu));
      p8[2*i+1] += bf2f((unsigned short)(v[i] >> 16));
    }
  }
#pragma unroll
  for (int e = 0; e < 8; ++e) {
    p8[e] += __shfl_xor(p8[e], 8, 64);
    p8[e] += __shfl_xor(p8[e], 16, 64);
    p8[e] += __shfl_xor(p8[e], 32, 64);
  }
  int lane = tid & 63, wv = tid >> 6;
  if (lane < 8) {
#pragma unroll
    for (int e = 0; e < 8; ++e) red2[wv*64 + lane*8 + e] = p8[e];
  }
  __syncthreads();
  if (tid < 64)
    atomicAdd(&fb[FO_XM + n*64 + tid],
              red2[tid] + red2[64+tid] + red2[128+tid] + red2[192+tid]);
}

// ---------------- k_p1b: win3/5 q-logits + xm, j-outer (no spill) -----------
template<int WIN, int CH, int CHUNK>
DEV void p1b_body(int idx, const float* wqs, float wqb) {
  using W = WP<WIN>;
  constexpr int K = W::K, P = W::P, CK = 64*K, QOFF = W::QOFF,
                BOFF = W::BOFF, EXO = W::EXO;
  float* fb = g_fb;
  const bf16* ex = (const bf16*)g_ex_u;
  int bi = idx / CH, ch = idx - bi*CH;
  int n = bi / P, bl = bi - n*P; int bg = BOFF + bi;
  int base = ch*CHUNK;
  const bf16* exn = ex + ((size_t)n*128 + EXO)*25600;
  float* qout = fb + FO_Q + QOFF + (size_t)bi*K + base;
  int tid = threadIdx.x, lane = tid & 63;
  int rel1 = 256 + tid; bool a1 = rel1 < CHUNK;
  int c0,k0,p0; decomp<WIN>(bl*CK + base + tid,  c0, k0, p0);
  int c1,k1,p1; decomp<WIN>(bl*CK + base + rel1, c1, k1, p1);
  float dot0 = 0.f, dot1 = 0.f;
  for (int j = 0; j < 64; ++j) {
    float w = wqs[j];
    float v0 = __bfloat162float(exn[c0*25600 + pix<WIN>(k0, p0)]);
    float v1 = a1 ? __bfloat162float(exn[c1*25600 + pix<WIN>(k1, p1)]) : 0.f;
    dot0 += w * v0; dot1 += w * v1;
    float ps = v0 + v1;
    ps += __shfl_xor(ps, 32, 64);
    ps += __shfl_xor(ps, 16, 64);
    ps += __shfl_xor(ps, 8, 64);
    ps += __shfl_xor(ps, 4, 64);
    ps += __shfl_xor(ps, 2, 64);
    ps += __shfl_xor(ps, 1, 64);
    if (lane == 0) atomicAdd(&fb[FO_XM + bg*64 + j], ps);
    stepK<WIN>(c0, k0, p0); stepK<WIN>(c1, k1, p1);
  }
  qout[tid] = dot0 + wqb;
  if (a1) qout[rel1] = dot1 + wqb;
}

__global__ __launch_bounds__(256)
void k_p1b(const float* __restrict__ chq_w, const float* __restrict__ chq_b) {
  __shared__ float wqs[64];
  if (threadIdx.x < 64) wqs[threadIdx.x] = chq_w[threadIdx.x];
  __syncthreads();
  float wqb = chq_b[0];
  int blk = blockIdx.x;
  if (blk < 864) p1b_body<3, 6, 486>(blk, wqs, wqb);
  else           p1b_body<5, 2, 512>(blk - 864, wqs, wqb);
}

// ---------------- k_bstats: per-b softmax stats + spatial branch ----------------
__global__ __launch_bounds__(256)
void k_bstats(const float* __restrict__ spq_w, const float* __restrict__ spq_b,
              const float* __restrict__ spv_w, const float* __restrict__ spv_b) {
  float* fb = g_fb;
  __shared__ float red[256]; __shared__ float sqs[32]; __shared__ float swq[32];
  int bg = blockIdx.x, tid = threadIdx.x;
  int Kk, qo, bi;
  if (bg < 16)       { Kk = 25600; qo = 0;      bi = bg;       }
  else if (bg < 160) { Kk = 2916;  qo = 409600; bi = bg - 16;  }
  else               { Kk = 1024;  qo = 829504; bi = bg - 160; }
  const float* lg = fb + FO_Q + qo + (size_t)bi*Kk;
  float m = -1e30f;
  for (int s = tid; s < Kk; s += 256) m = fmaxf(m, lg[s]);
  red[tid] = m; __syncthreads();
  for (int st = 128; st; st >>= 1) { if (tid < st) red[tid] = fmaxf(red[tid], red[tid+st]); __syncthreads(); }
  float M = red[0]; __syncthreads();
  float ss = 0.f;
  for (int s = tid; s < Kk; s += 256) ss += __expf(lg[s] - M);
  red[tid] = ss; __syncthreads();
  for (int st = 128; st; st >>= 1) { if (tid < st) red[tid] += red[tid+st]; __syncthreads(); }
  if (tid == 0) { fb[FO_BM + bg] = M; fb[FO_BINV + bg] = 1.f / red[0]; }
  const float* xm_b = fb + FO_XM + bg*64;
  float rK = 1.f / (float)Kk;
  if (tid < 32) {
    float a = spq_b[tid];
    for (int c = 0; c < 64; ++c)
      a += spq_w[tid*64 + c] * (xm_b[c] * rK);
    sqs[tid] = a;
  }
  __syncthreads();
  if (tid == 0) {
    float mx = -1e30f;
    for (int o = 0; o < 32; ++o) mx = fmaxf(mx, sqs[o]);
    float z = 0.f;
    for (int o = 0; o < 32; ++o) { float e = __expf(sqs[o] - mx); swq[o] = e; z += e; }
    float rz = 1.f / z;
    for (int o = 0; o < 32; ++o) swq[o] *= rz;
  }
  __syncthreads();
  if (tid < 64) {
    float a = 0.f;
    for (int o = 0; o < 32; ++o) a += swq[o] * spv_w[o*64 + tid];
    fb[FO_G + bg*64 + tid] = a;
  }
  if (tid == 64) {
    float gb = 0.f;
    for (int o = 0; o < 32; ++o) gb += swq[o] * spv_b[o];
    fb[FO_GB + bg] = gb;
  }
}

// ---------------- k_smt1: win1 smap + t (streaming over ex2) ----------------
__global__ __launch_bounds__(256)
void k_smt1() {
  __shared__ float gss[64];
  __shared__ float red2[256];
  float* fb = g_fb;
  const bf16* ex2 = (const bf16*)g_ex2_u;
  int blk = blockIdx.x; int n = blk / 50; int sbase = (blk % 50) * 512;
  int tid = threadIdx.x;
  if (tid < 64) gss[tid] = fb[FO_G + n*64 + tid];
  __syncthreads();
  float gbs = fb[FO_GB + n];
  float M = fb[FO_BM + n], inv = fb[FO_BINV + n];
  // phase 1: smap
  for (int it = 0; it < 2; ++it) {
    int sp = sbase + it*256 + tid;
    const u32x4* e2 = (const u32x4*)(ex2 + (size_t)(n*25600 + sp)*256);
    float dot = 0.f;
#pragma unroll
    for (int r = 0; r < 8; ++r) {
      u32x4 v = e2[r];
#pragma unroll
      for (int i = 0; i < 4; ++i) {
        int c = r*8 + 2*i;
        dot += gss[c]   * bf2f((unsigned short)(v[i] & 0xffffu));
        dot += gss[c+1] * bf2f((unsigned short)(v[i] >> 16));
      }
    }
    fb[FO_SMAP + (size_t)n*25600 + sp] = 1.f / (1.f + __expf(-(dot + gbs)));
  }
  // phase 2: t[c] += qv-weighted column sums
  int oct = tid & 7, rb = tid >> 3;
  float p8[8];
#pragma unroll
  for (int e = 0; e < 8; ++e) p8[e] = 0.f;
  for (int it = 0; it < 16; ++it) {
    int row = sbase + rb + it*32;
    float qv = __expf(fb[FO_Q + (size_t)n*25600 + row] - M) * inv;
    u32x4 v = *(const u32x4*)(ex2 + (size_t)(n*25600 + row)*256 + oct*8);
#pragma unroll
    for (int i = 0; i < 4; ++i) {
      p8[2*i]   += qv * bf2f((unsigned short)(v[i] & 0xffffu));
      p8[2*i+1] += qv * bf2f((unsigned short)(v[i] >> 16));
    }
  }
#pragma unroll
  for (int e = 0; e < 8; ++e) {
    p8[e] += __shfl_xor(p8[e], 8, 64);
    p8[e] += __shfl_xor(p8[e], 16, 64);
    p8[e] += __shfl_xor(p8[e], 32, 64);
  }
  int lane = tid & 63, wv = tid >> 6;
  if (lane < 8) {
#pragma unroll
    for (int e = 0; e < 8; ++e) red2[wv*64 + lane*8 + e] = p8[e];
  }
  __syncthreads();
  if (tid < 64)
    atomicAdd(&fb[FO_T + n*64 + tid],
              red2[tid] + red2[64+tid] + red2[128+tid] + red2[192+tid]);
}

// ---------------- k_p2b: win3/5 smap + t, j-outer (no spill) ----------------
template<int WIN, int CH, int CHUNK>
DEV void p2b_body(int idx, const float* gss) {
  using W = WP<WIN>;
  constexpr int K = W::K, P = W::P, CK = 64*K, QOFF = W::QOFF,
                BOFF = W::BOFF, EXO = W::EXO;
  float* fb = g_fb;
  const bf16* ex = (const bf16*)g_ex_u;
  int bi = idx / CH, ch = idx - bi*CH;
  int n = bi / P, bl = bi - n*P; int bg = BOFF + bi;
  int base = ch*CHUNK;
  const bf16* exn = ex + ((size_t)n*128 + EXO)*25600;
  const float* qin = fb + FO_Q + QOFF + (size_t)bi*K + base;
  float* so = fb + FO_SMAP + QOFF + (size_t)bi*K + base;
  float M = fb[FO_BM + bg], inv = fb[FO_BINV + bg];
  float gbs = fb[FO_GB + bg];
  int tid = threadIdx.x, lane = tid & 63;
  int rel1 = 256 + tid; bool a1 = rel1 < CHUNK;
  int c0,k0,p0; decomp<WIN>(bl*CK + base + tid,  c0, k0, p0);
  int c1,k1,p1; decomp<WIN>(bl*CK + base + rel1, c1, k1, p1);
  float qv0 = __expf(qin[tid] - M) * inv;
  float qv1 = a1 ? (__expf(qin[rel1] - M) * inv) : 0.f;
  float dot0 = 0.f, dot1 = 0.f;
  for (int j = 0; j < 64; ++j) {
    float g = gss[j];
    float v0 = __bfloat162float(exn[c0*25600 + pix<WIN>(k0, p0)]);
    float v1 = a1 ? __bfloat162float(exn[c1*25600 + pix<WIN>(k1, p1)]) : 0.f;
    dot0 += g * v0; dot1 += g * v1;
    float tp = qv0 * v0 + qv1 * v1;
    tp += __shfl_xor(tp, 32, 64);
    tp += __shfl_xor(tp, 16, 64);
    tp += __shfl_xor(tp, 8, 64);
    tp += __shfl_xor(tp, 4, 64);
    tp += __shfl_xor(tp, 2, 64);
    tp += __shfl_xor(tp, 1, 64);
    if (lane == 0) atomicAdd(&fb[FO_T + bg*64 + j], tp);
    stepK<WIN>(c0, k0, p0); stepK<WIN>(c1, k1, p1);
  }
  so[tid] = 1.f / (1.f + __expf(-(dot0 + gbs)));
  if (a1) so[rel1] = 1.f / (1.f + __expf(-(dot1 + gbs)));
}

__global__ __launch_bounds__(256)
void k_p2b() {
  __shared__ float gss[64];
  float* fb = g_fb;
  int blk = blockIdx.x;
  int bg;
  if (blk < 864) bg = 16 + blk / 6;
  else           bg = 160 + (blk - 864) / 2;
  if (threadIdx.x < 64) gss[threadIdx.x] = fb[FO_G + bg*64 + threadIdx.x];
  __syncthreads();
  if (blk < 864) p2b_body<3, 6, 486>(blk, gss);
  else           p2b_body<5, 2, 512>(blk - 864, gss);
}

// ---------------- k_zln: wz -> z -> LayerNorm -> sigA ----------------
__global__ __launch_bounds__(64)
void k_zln(const float* __restrict__ chv_w, const float* __restrict__ chv_b,
           const float* __restrict__ chz_w, const float* __restrict__ chz_b,
           const float* __restrict__ ln_g,  const float* __restrict__ ln_b) {
  float* fb = g_fb;
  __shared__ float wzs[32]; __shared__ float zsh[64]; __shared__ float mom[2];
  int bg = blockIdx.x, tid = threadIdx.x;
  const float* t_b = fb + FO_T + bg*64;
  if (tid < 32) {
    float a = chv_b[tid];
    for (int c = 0; c < 64; ++c)
      a += chv_w[tid*64 + c] * t_b[c];
    wzs[tid] = a;
  }
  __syncthreads();
  float zv = chz_b[tid];
  for (int o = 0; o < 32; ++o)
    zv += chz_w[tid*32 + o] * wzs[o];
  zsh[tid] = zv;
  __syncthreads();
  if (tid == 0) {
    float mu = 0.f;
    for (int j = 0; j < 64; ++j) mu += zsh[j];
    mu *= (1.f/64.f);
    float m2 = 0.f;
    for (int j = 0; j < 64; ++j) { float d = zsh[j] - mu; m2 += d*d; }
    m2 *= (1.f/64.f);
    mom[0] = mu; mom[1] = rsqrtf(m2 + 1e-5f);
  }
  __syncthreads();
  float zn = (zv - mom[0]) * mom[1] * ln_g[tid] + ln_b[tid];
  fb[FO_SIGA + bg*64 + tid] = 1.f / (1.f + __expf(-zn));
}

// ---------------- k_final: gates -> extT (bf16, swizzled LDS) -> MFMA conv ----
template<int WIN> DEV void gate_rows3(int n, int s, int h, int w, int px,
                                      const float* __restrict__ fb,
                                      const bf16* __restrict__ e2row,
                                      bf16* extT) {
  using W = WP<WIN>;
  constexpr int SH = W::SH, KH = W::KH, K = W::K, P = W::P, WI = W::WI,
                QOFF = W::QOFF, BOFF = W::BOFF;
  const float* smap = fb + FO_SMAP + QOFF + (size_t)(n*P)*K;
  const float* sg   = fb + FO_SIGA + (size_t)(BOFF + n*P)*64;
  const u32x4* src = (const u32x4*)(e2row + WI*64);
  u32x4 vv[8];
#pragma unroll
  for (int r = 0; r < 8; ++r) vv[r] = src[r];
  int swz = (px & 7) << 3;
  unsigned short ob[8];
  if constexpr (WIN == 1) {
    float sm = smap[s];
#pragma unroll
    for (int r = 0; r < 8; ++r) {
#pragma unroll
      for (int i = 0; i < 4; ++i) {
        int c = r*8 + 2*i;
        float lo = bf2f((unsigned short)(vv[r][i] & 0xffffu));
        float hi = bf2f((unsigned short)(vv[r][i] >> 16));
        ob[2*i]   = bfbits(lo * (1.f + sg[c]   + sm));
        ob[2*i+1] = bfbits(hi * (1.f + sg[c+1] + sm));
      }
      store8bf(&extT[px*256 + ((WI*64 + r*8) ^ swz)], ob);
    }
  } else {
    int phmin = (h >= KH) ? (h - KH)/SH + 1 : 0;
    int phmax = (WIN-1 < h/SH) ? WIN-1 : h/SH;
    int pwmin = (w >= KH) ? (w - KH)/SH + 1 : 0;
    int pwmax = (WIN-1 < w/SH) ? WIN-1 : w/SH;
    int cf[4]; int s0s[4]; int np = 0;
    for (int ph = phmin; ph <= phmax; ++ph)
      for (int pw = pwmin; pw <= pwmax; ++pw) {
        int ki = h - ph*SH, kj = w - pw*SH;
        unsigned base0 = (unsigned)((ki*KH + kj)*P + ph*WIN + pw);
        unsigned q = base0 / (unsigned)K;
        cf[np] = (int)q; s0s[np] = (int)(base0 - q*(unsigned)K); ++np;
      }
    float rc = 1.f / (float)np;
    int hi4[4]; float smv[4];
#pragma unroll
    for (int t = 0; t < 4; ++t)
      if (t < np) { hi4[t] = cf[t] >> 6; smv[t] = smap[hi4[t]*K + s0s[t]]; }
#pragma unroll
    for (int r = 0; r < 8; ++r) {
#pragma unroll
      for (int cc = 0; cc < 8; ++cc) {
        float gsum = 0.f;
#pragma unroll
        for (int t = 0; t < 4; ++t) {
          if (t < np) {
            int v = cf[t];
            int h2 = v >> 6;
            if (h2 != hi4[t]) { hi4[t] = h2; smv[t] = smap[h2*K + s0s[t]]; }
            gsum += sg[v] + smv[t];
            cf[t] = v + P;
          }
        }
        unsigned wd = vv[r][cc >> 1];
        unsigned short eb = (cc & 1) ? (unsigned short)(wd >> 16)
                                     : (unsigned short)(wd & 0xffffu);
        ob[cc] = bfbits(bf2f(eb) * (1.f + gsum * rc));
      }
      store8bf(&extT[px*256 + ((WI*64 + r*8) ^ swz)], ob);
    }
  }
}

__global__ __launch_bounds__(256)
void k_final(float* __restrict__ out) {
  const float* fb = g_fb;
  const bf16* ex2 = (const bf16*)g_ex2_u;
  __shared__ __align__(16) bf16 extT[64*256];   // [px][k] swizzled, 32 KB
  int blk = blockIdx.x; int n = blk / 400; int s0 = (blk % 400) * 64;
  int tid = threadIdx.x;
  int rg = tid >> 6; int px = tid & 63;
  int s = s0 + px; int h = s / 160; int w = s - h*160;
  const bf16* e2row = ex2 + (size_t)(n*25600 + s)*256;
  if (rg == 3) {
    const u32x4* src = (const u32x4*)(e2row + 192);
    int swz = (px & 7) << 3;
#pragma unroll
    for (int r = 0; r < 8; ++r)
      *(u32x4*)&extT[px*256 + ((192 + r*8) ^ swz)] = src[r];
  } else if (rg == 0) gate_rows3<1>(n, s, h, w, px, fb, e2row, extT);
  else if (rg == 1)   gate_rows3<3>(n, s, h, w, px, fb, e2row, extT);
  else                gate_rows3<5>(n, s, h, w, px, fb, e2row, extT);
  __syncthreads();

  // ---- MFMA: out[o][px] = sum_k W[k][o] * extT[px][k], K=256 ----
  int wv = tid >> 6; int l = tid & 63;
  int lx = l & 15, g = l >> 4;
  const u32x4* wfA = (const u32x4*)(fb + FO_WFRAG);
  u32x4 af[8];
#pragma unroll
  for (int ks = 0; ks < 8; ++ks) af[ks] = wfA[(wv*8 + ks)*64 + l];
  f32x4 acc[4];
#pragma unroll
  for (int pt = 0; pt < 4; ++pt) acc[pt] = f32x4{0.f, 0.f, 0.f, 0.f};
#pragma unroll
  for (int ks = 0; ks < 8; ++ks) {
#pragma unroll
    for (int pt = 0; pt < 4; ++pt) {
      int pxx = pt*16 + lx;
      const u32x4* bp = (const u32x4*)&extT[pxx*256 + ((ks*32 + g*8) ^ ((pxx & 7) << 3))];
      acc[pt] = __builtin_amdgcn_mfma_f32_16x16x32_bf16(
                  as_bf16x8(af[ks]), as_bf16x8(*bp), acc[pt], 0, 0, 0);
    }
  }
  float bia[4];
#pragma unroll
  for (int r = 0; r < 4; ++r) bia[r] = fb[FO_BCOMB + wv*16 + g*4 + r];
#pragma unroll
  for (int pt = 0; pt < 4; ++pt) {
#pragma unroll
    for (int r = 0; r < 4; ++r)
      out[(size_t)(n*64 + wv*16 + g*4 + r)*25600 + s0 + pt*16 + lx] = acc[pt][r] + bia[r];
  }
}

// ---------------- launch ----------------
extern "C" void kernel_launch(void* const* d_in, const int* in_sizes, int n_in,
                              void* d_out, int out_size, void* d_ws, size_t ws_size,
                              hipStream_t stream) {
  const float* x     = (const float*)d_in[0];
  const float* exp_w = (const float*)d_in[1];
  const float* exp_b = (const float*)d_in[2];
  const float* res_w = (const float*)d_in[3];
  const float* res_b = (const float*)d_in[4];
  const float* fus_w = (const float*)d_in[5];
  const float* fus_b = (const float*)d_in[6];
  const float* chv_w = (const float*)d_in[7];
  const float* chv_b = (const float*)d_in[8];
  const float* chq_w = (const float*)d_in[9];
  const float* chq_b = (const float*)d_in[10];
  const float* chz_w = (const float*)d_in[11];
  const float* chz_b = (const float*)d_in[12];
  const float* ln_g  = (const float*)d_in[13];
  const float* ln_b  = (const float*)d_in[14];
  const float* spv_w = (const float*)d_in[15];
  const float* spv_b = (const float*)d_in[16];
  const float* spq_w = (const float*)d_in[17];
  const float* spq_b = (const float*)d_in[18];
  float* out = (float*)d_out;

  k_prep<<<393, 256, 0, stream>>>(exp_w, exp_b, res_w, res_b, fus_w, fus_b);
  k_prep2<<<64, 256, 0, stream>>>();
  k_ex<<<6400, 256, 0, stream>>>(x);

  k_q1x<<<800, 256, 0, stream>>>(chq_w, chq_b);
  k_p1b<<<1664, 256, 0, stream>>>(chq_w, chq_b);

  k_bstats<<<560, 256, 0, stream>>>(spq_w, spq_b, spv_w, spv_b);

  k_smt1<<<800, 256, 0, stream>>>();
  k_p2b<<<1664, 256, 0, stream>>>();

  k_zln<<<560, 64, 0, stream>>>(chv_w, chv_b, chz_w, chz_b, ln_g, ln_b);

  k_final<<<6400, 256, 0, stream>>>(out);
}

// Round 9
// 735.190 us; speedup vs baseline: 3.3173x; 1.2574x over previous
//
#include <hip/hip_runtime.h>
#include <hip/hip_bf16.h>

typedef __hip_bfloat16 bf16;
typedef __attribute__((ext_vector_type(4))) unsigned int u32x4;
typedef __attribute__((ext_vector_type(4))) float f32x4;
typedef __attribute__((ext_vector_type(8))) short bf16x8;
#define DEV __device__ __forceinline__

// ---------------- problem constants ----------------
// N=16, C=64, H=W=160, S=25600, expanded channels 192, windows {1,3,5}

// fp32 scratch layout (offsets in floats)
constexpr int FO_Q     = 0;         // raw logits (win1 region becomes qv after k_sm1)
constexpr int FO_SMAP  = 1239104;   // sigmoid spatial gate (1239104)
constexpr int FO_XM    = 2478208;   // per-(b,c') channel sums (560*64)
constexpr int FO_T     = 2514048;   // per-(b,c') q-weighted sums (560*64)
constexpr int FO_SIGA  = 2549888;   // per-(b,c') channel gate sigmoid(zn) (560*64)
constexpr int FO_G     = 2585728;   // per-(b,c') spatial-branch weights (560*64)
constexpr int FO_BM    = 2621568;   // per-b logit max (560)
constexpr int FO_BINV  = 2622128;   // per-b 1/sum(exp) (560)
constexpr int FO_GB    = 2622688;   // per-b spatial bias term (560)
constexpr int FO_EXPT  = 2623248;   // exp_w transposed [c*192+o] (12288)
constexpr int FO_EXPB  = 2635536;   // exp_b fp32 (192)
constexpr int FO_WBIGT = 2635728;   // combined final weight [k*64+f], k<256 (16384)
constexpr int FO_BCOMB = 2652112;   // combined final bias (64)
constexpr int FO_WFRAG = 2652176;   // bf16 A-fragment-ordered weights (16384 bf16)
constexpr int FB_SIZE  = 2660368;

__device__ unsigned short g_ex_u[78643200];   // ex [n][192ch][25600s] bf16 (single layout)
__device__ float          g_fb[FB_SIZE];

template<int WIN> struct WP;
template<> struct WP<1> { static constexpr int WI=0, SH=160, KH=160, K=25600, P=1,  B=16,  QOFF=0,      BOFF=0,   EXO=0;   };
template<> struct WP<3> { static constexpr int WI=1, SH=53,  KH=54,  K=2916,  P=9,  B=144, QOFF=409600, BOFF=16,  EXO=64;  };
template<> struct WP<5> { static constexpr int WI=2, SH=32,  KH=32,  K=1024,  P=25, B=400, QOFF=829504, BOFF=160, EXO=128; };

// psa-space walk helpers (used by win3/5 pass kernels)
template<int WIN> DEV void decomp(int f, int& c, int& kidx, int& p) {
  constexpr int P = WP<WIN>::P, K = WP<WIN>::K;
  int m;
  if constexpr (P == 1) { p = 0; m = f; }
  else { m = f / P; p = f - m * P; }
  c = m / K; kidx = m - c * K;
}

template<int WIN> DEV void stepK(int& c, int& kidx, int& p) {  // f += K
  constexpr int K = WP<WIN>::K, P = WP<WIN>::P;
  if constexpr (P == 1) { kidx += K; }
  else {
    constexpr int KMP = K % P, KDP = K / P;
    if constexpr (KMP == 0) { kidx += KDP; }
    else { p += KMP; if (p >= P) { p -= P; kidx += KDP + 1; } else kidx += KDP; }
  }
  if (kidx >= K) { kidx -= K; ++c; }
}

template<int WIN> DEV int pix(int kidx, int p) {
  constexpr int KH = WP<WIN>::KH, SH = WP<WIN>::SH;
  if constexpr (WIN == 1) return kidx;
  int ki = kidx / KH, kj = kidx - ki * KH;
  int ph = p / WIN,  pw = p - ph * WIN;
  return (ph * SH + ki) * 160 + pw * SH + kj;
}

DEV float bf2f(unsigned short u) {
  bf16 b;
  __builtin_memcpy(&b, &u, 2);
  return __bfloat162float(b);
}

DEV bf16x8 as_bf16x8(u32x4 v) {
  union { u32x4 u; bf16x8 b; } x; x.u = v; return x.b;
}

// ---------------- k_prep ----------------
__global__ __launch_bounds__(256)
void k_prep(const float* __restrict__ exp_w, const float* __restrict__ exp_b,
            const float* __restrict__ res_w, const float* __restrict__ res_b,
            const float* __restrict__ fus_w, const float* __restrict__ fus_b) {
  float* fb = g_fb;
  int gt = blockIdx.x * 256 + threadIdx.x;
  if (gt < 12288) {                       // Wcomb[f][oc] = sum_o fus[f][o]*res[o][oc]
    int oc = gt % 192, f = gt / 192;
    float a = 0.f;
    for (int o = 0; o < 64; ++o)
      a += fus_w[f*64+o] * res_w[o*192+oc];
    fb[FO_WBIGT + oc*64 + f] = a;
  } else if (gt < 16384) {                // rows 192..255: fus_w
    int t2 = gt - 12288; int o = t2 % 64, f = t2 / 64;
    fb[FO_WBIGT + (192+o)*64 + f] = fus_w[f*64+o];
  } else if (gt < 16448) {                // bcomb
    int f = gt - 16384;
    float a = fus_b[f];
    for (int o = 0; o < 64; ++o)
      a += fus_w[f*64+o] * res_b[o];
    fb[FO_BCOMB + f] = a;
  } else if (gt < 28736) {                // expT[c*192+o] = exp_w[o][c]
    int t3 = gt - 16448; int o = t3 % 192, c = t3 / 192;
    fb[FO_EXPT + c*192 + o] = exp_w[o*64+c];
  } else if (gt < 28928) {
    int o = gt - 28736;
    fb[FO_EXPB + o] = exp_b[o];
  } else if (gt < 28928 + 71680) {        // zero xm and t (contiguous)
    fb[FO_XM + gt - 28928] = 0.f;
  }
}

// ---------------- k_prep2: bake bf16 A-fragments for the final MFMA ----------
__global__ __launch_bounds__(256)
void k_prep2() {
  float* fb = g_fb;
  bf16* wf = (bf16*)(fb + FO_WFRAG);
  int t = blockIdx.x * 256 + threadIdx.x;     // 0..16383
  int j  = t & 7;
  int l  = (t >> 3) & 63;
  int ks = (t >> 9) & 7;
  int wv = t >> 12;
  int k = ks*32 + (l >> 4)*8 + j;
  int o = wv*16 + (l & 15);
  wf[t] = __float2bfloat16(fb[FO_WBIGT + k*64 + o]);
}

// ---------------- k_ex: ex = conv1x1(x, exp_w, exp_b), channel-major --------
__global__ __launch_bounds__(256)
void k_ex(const float* __restrict__ x) {
  const float* fb = g_fb;
  bf16* ex = (bf16*)g_ex_u;
  __shared__ float xs[64*64];
  int blk = blockIdx.x; int n = blk / 400; int s0 = (blk % 400) * 64;
  int tid = threadIdx.x;
  for (int e = tid; e < 4096; e += 256) {
    int c = e >> 6, px = e & 63;
    xs[e] = x[(n*64 + c)*25600 + s0 + px];
  }
  __syncthreads();
  int px = tid & 63;
  int o0 = __builtin_amdgcn_readfirstlane((tid >> 6) * 48);
  float acc[48];
#pragma unroll
  for (int j = 0; j < 48; ++j) acc[j] = fb[FO_EXPB + o0 + j];
  const float* wT = fb + FO_EXPT;
  for (int c = 0; c < 64; ++c) {
    float xv = xs[(c << 6) + px];
    const float* wr = wT + c*192 + o0;
#pragma unroll
    for (int j = 0; j < 48; ++j) acc[j] += wr[j] * xv;
  }
  bf16* eo = ex + ((size_t)n*192 + o0)*25600 + s0 + px;
#pragma unroll
  for (int j = 0; j < 48; ++j) eo[(size_t)j*25600] = __float2bfloat16(acc[j]);
}

// ---------------- k_q1: win1 logits, streaming coalesced over ex ------------
__global__ __launch_bounds__(256)
void k_q1(const float* __restrict__ chq_w, const float* __restrict__ chq_b) {
  __shared__ float wqs[64];
  float* fb = g_fb;
  const bf16* ex = (const bf16*)g_ex_u;
  int blk = blockIdx.x; int n = blk / 100; int sp = (blk % 100)*256 + threadIdx.x;
  if (threadIdx.x < 64) wqs[threadIdx.x] = chq_w[threadIdx.x];
  __syncthreads();
  const bf16* col = ex + (size_t)n*192*25600 + sp;
  float dot = 0.f;
#pragma unroll 8
  for (int c = 0; c < 64; ++c)
    dot += wqs[c] * __bfloat162float(col[(size_t)c*25600]);
  fb[FO_Q + (size_t)n*25600 + sp] = dot + chq_b[0];
}

// ---------------- k_xm: win1 xm[c] = row-sum of ex[c] -----------------------
__global__ __launch_bounds__(256)
void k_xm() {
  __shared__ float red[256];
  float* fb = g_fb;
  const bf16* ex = (const bf16*)g_ex_u;
  int blk = blockIdx.x; int n = blk >> 6; int c = blk & 63;
  const bf16* row = ex + ((size_t)n*192 + c)*25600;
  int tid = threadIdx.x;
  float a = 0.f;
  for (int it = 0; it < 13; ++it) {
    int o = it*256 + tid;
    if (o < 3200) {
      u32x4 v = *(const u32x4*)(row + o*8);
#pragma unroll
      for (int i = 0; i < 4; ++i) {
        a += bf2f((unsigned short)(v[i] & 0xffffu));
        a += bf2f((unsigned short)(v[i] >> 16));
      }
    }
  }
  red[tid] = a; __syncthreads();
  for (int st = 128; st; st >>= 1) { if (tid < st) red[tid] += red[tid+st]; __syncthreads(); }
  if (tid == 0) fb[FO_XM + n*64 + c] = red[0];
}

// ---------------- k_p1b: win3/5 q-logits + xm, j-outer (no spill) -----------
template<int WIN, int CH, int CHUNK>
DEV void p1b_body(int idx, const float* wqs, float wqb) {
  using W = WP<WIN>;
  constexpr int K = W::K, P = W::P, CK = 64*K, QOFF = W::QOFF,
                BOFF = W::BOFF, EXO = W::EXO;
  float* fb = g_fb;
  const bf16* ex = (const bf16*)g_ex_u;
  int bi = idx / CH, ch = idx - bi*CH;
  int n = bi / P, bl = bi - n*P; int bg = BOFF + bi;
  int base = ch*CHUNK;
  const bf16* exn = ex + ((size_t)n*192 + EXO)*25600;
  float* qout = fb + FO_Q + QOFF + (size_t)bi*K + base;
  int tid = threadIdx.x, lane = tid & 63;
  int rel1 = 256 + tid; bool a1 = rel1 < CHUNK;
  int c0,k0,p0; decomp<WIN>(bl*CK + base + tid,  c0, k0, p0);
  int c1,k1,p1; decomp<WIN>(bl*CK + base + rel1, c1, k1, p1);
  float dot0 = 0.f, dot1 = 0.f;
  for (int j = 0; j < 64; ++j) {
    float w = wqs[j];
    float v0 = __bfloat162float(exn[c0*25600 + pix<WIN>(k0, p0)]);
    float v1 = a1 ? __bfloat162float(exn[c1*25600 + pix<WIN>(k1, p1)]) : 0.f;
    dot0 += w * v0; dot1 += w * v1;
    float ps = v0 + v1;
    ps += __shfl_xor(ps, 32, 64);
    ps += __shfl_xor(ps, 16, 64);
    ps += __shfl_xor(ps, 8, 64);
    ps += __shfl_xor(ps, 4, 64);
    ps += __shfl_xor(ps, 2, 64);
    ps += __shfl_xor(ps, 1, 64);
    if (lane == 0) atomicAdd(&fb[FO_XM + bg*64 + j], ps);
    stepK<WIN>(c0, k0, p0); stepK<WIN>(c1, k1, p1);
  }
  qout[tid] = dot0 + wqb;
  if (a1) qout[rel1] = dot1 + wqb;
}

__global__ __launch_bounds__(256)
void k_p1b(const float* __restrict__ chq_w, const float* __restrict__ chq_b) {
  __shared__ float wqs[64];
  if (threadIdx.x < 64) wqs[threadIdx.x] = chq_w[threadIdx.x];
  __syncthreads();
  float wqb = chq_b[0];
  int blk = blockIdx.x;
  if (blk < 864) p1b_body<3, 6, 486>(blk, wqs, wqb);
  else           p1b_body<5, 2, 512>(blk - 864, wqs, wqb);
}

// ---------------- k_bstats: per-b softmax stats + spatial branch ----------------
__global__ __launch_bounds__(256)
void k_bstats(const float* __restrict__ spq_w, const float* __restrict__ spq_b,
              const float* __restrict__ spv_w, const float* __restrict__ spv_b) {
  float* fb = g_fb;
  __shared__ float red[256]; __shared__ float sqs[32]; __shared__ float swq[32];
  int bg = blockIdx.x, tid = threadIdx.x;
  int Kk, qo, bi;
  if (bg < 16)       { Kk = 25600; qo = 0;      bi = bg;       }
  else if (bg < 160) { Kk = 2916;  qo = 409600; bi = bg - 16;  }
  else               { Kk = 1024;  qo = 829504; bi = bg - 160; }
  const float* lg = fb + FO_Q + qo + (size_t)bi*Kk;
  float m = -1e30f;
  for (int s = tid; s < Kk; s += 256) m = fmaxf(m, lg[s]);
  red[tid] = m; __syncthreads();
  for (int st = 128; st; st >>= 1) { if (tid < st) red[tid] = fmaxf(red[tid], red[tid+st]); __syncthreads(); }
  float M = red[0]; __syncthreads();
  float ss = 0.f;
  for (int s = tid; s < Kk; s += 256) ss += __expf(lg[s] - M);
  red[tid] = ss; __syncthreads();
  for (int st = 128; st; st >>= 1) { if (tid < st) red[tid] += red[tid+st]; __syncthreads(); }
  if (tid == 0) { fb[FO_BM + bg] = M; fb[FO_BINV + bg] = 1.f / red[0]; }
  const float* xm_b = fb + FO_XM + bg*64;
  float rK = 1.f / (float)Kk;
  if (tid < 32) {
    float a = spq_b[tid];
    for (int c = 0; c < 64; ++c)
      a += spq_w[tid*64 + c] * (xm_b[c] * rK);
    sqs[tid] = a;
  }
  __syncthreads();
  if (tid == 0) {
    float mx = -1e30f;
    for (int o = 0; o < 32; ++o) mx = fmaxf(mx, sqs[o]);
    float z = 0.f;
    for (int o = 0; o < 32; ++o) { float e = __expf(sqs[o] - mx); swq[o] = e; z += e; }
    float rz = 1.f / z;
    for (int o = 0; o < 32; ++o) swq[o] *= rz;
  }
  __syncthreads();
  if (tid < 64) {
    float a = 0.f;
    for (int o = 0; o < 32; ++o) a += swq[o] * spv_w[o*64 + tid];
    fb[FO_G + bg*64 + tid] = a;
  }
  if (tid == 64) {
    float gb = 0.f;
    for (int o = 0; o < 32; ++o) gb += swq[o] * spv_b[o];
    fb[FO_GB + bg] = gb;
  }
}

// ---------------- k_sm1: win1 smap + qv (overwrites Q win1 region) ----------
__global__ __launch_bounds__(256)
void k_sm1() {
  __shared__ float gss[64];
  float* fb = g_fb;
  const bf16* ex = (const bf16*)g_ex_u;
  int blk = blockIdx.x; int n = blk / 100; int sp = (blk % 100)*256 + threadIdx.x;
  if (threadIdx.x < 64) gss[threadIdx.x] = fb[FO_G + n*64 + threadIdx.x];
  __syncthreads();
  float M = fb[FO_BM + n], inv = fb[FO_BINV + n], gb = fb[FO_GB + n];
  const bf16* col = ex + (size_t)n*192*25600 + sp;
  float dot = 0.f;
#pragma unroll 8
  for (int c = 0; c < 64; ++c)
    dot += gss[c] * __bfloat162float(col[(size_t)c*25600]);
  float q = fb[FO_Q + (size_t)n*25600 + sp];
  fb[FO_Q + (size_t)n*25600 + sp] = __expf(q - M) * inv;   // qv for k_t1
  fb[FO_SMAP + (size_t)n*25600 + sp] = 1.f / (1.f + __expf(-(dot + gb)));
}

// ---------------- k_t1: win1 t[c] = sum_s qv[s]*ex[c][s] --------------------
__global__ __launch_bounds__(256)
void k_t1() {
  __shared__ float red[256];
  float* fb = g_fb;
  const bf16* ex = (const bf16*)g_ex_u;
  int blk = blockIdx.x; int n = blk >> 6; int c = blk & 63;
  const bf16* row = ex + ((size_t)n*192 + c)*25600;
  const float* qv = fb + FO_Q + (size_t)n*25600;
  int tid = threadIdx.x;
  float a = 0.f;
  for (int it = 0; it < 13; ++it) {
    int o = it*256 + tid;
    if (o < 3200) {
      u32x4 v = *(const u32x4*)(row + o*8);
      f32x4 qa = *(const f32x4*)(qv + o*8);
      f32x4 qb = *(const f32x4*)(qv + o*8 + 4);
#pragma unroll
      for (int i = 0; i < 4; ++i) {
        float lo = bf2f((unsigned short)(v[i] & 0xffffu));
        float hi = bf2f((unsigned short)(v[i] >> 16));
        float q0 = (2*i < 4) ? qa[2*i] : qb[2*i-4];
        float q1 = (2*i+1 < 4) ? qa[2*i+1] : qb[2*i+1-4];
        a += q0 * lo + q1 * hi;
      }
    }
  }
  red[tid] = a; __syncthreads();
  for (int st = 128; st; st >>= 1) { if (tid < st) red[tid] += red[tid+st]; __syncthreads(); }
  if (tid == 0) fb[FO_T + n*64 + c] = red[0];
}

// ---------------- k_p2b: win3/5 smap + t, j-outer (no spill) ----------------
template<int WIN, int CH, int CHUNK>
DEV void p2b_body(int idx, const float* gss) {
  using W = WP<WIN>;
  constexpr int K = W::K, P = W::P, CK = 64*K, QOFF = W::QOFF,
                BOFF = W::BOFF, EXO = W::EXO;
  float* fb = g_fb;
  const bf16* ex = (const bf16*)g_ex_u;
  int bi = idx / CH, ch = idx - bi*CH;
  int n = bi / P, bl = bi - n*P; int bg = BOFF + bi;
  int base = ch*CHUNK;
  const bf16* exn = ex + ((size_t)n*192 + EXO)*25600;
  const float* qin = fb + FO_Q + QOFF + (size_t)bi*K + base;
  float* so = fb + FO_SMAP + QOFF + (size_t)bi*K + base;
  float M = fb[FO_BM + bg], inv = fb[FO_BINV + bg];
  float gbs = fb[FO_GB + bg];
  int tid = threadIdx.x, lane = tid & 63;
  int rel1 = 256 + tid; bool a1 = rel1 < CHUNK;
  int c0,k0,p0; decomp<WIN>(bl*CK + base + tid,  c0, k0, p0);
  int c1,k1,p1; decomp<WIN>(bl*CK + base + rel1, c1, k1, p1);
  float qv0 = __expf(qin[tid] - M) * inv;
  float qv1 = a1 ? (__expf(qin[rel1] - M) * inv) : 0.f;
  float dot0 = 0.f, dot1 = 0.f;
  for (int j = 0; j < 64; ++j) {
    float g = gss[j];
    float v0 = __bfloat162float(exn[c0*25600 + pix<WIN>(k0, p0)]);
    float v1 = a1 ? __bfloat162float(exn[c1*25600 + pix<WIN>(k1, p1)]) : 0.f;
    dot0 += g * v0; dot1 += g * v1;
    float tp = qv0 * v0 + qv1 * v1;
    tp += __shfl_xor(tp, 32, 64);
    tp += __shfl_xor(tp, 16, 64);
    tp += __shfl_xor(tp, 8, 64);
    tp += __shfl_xor(tp, 4, 64);
    tp += __shfl_xor(tp, 2, 64);
    tp += __shfl_xor(tp, 1, 64);
    if (lane == 0) atomicAdd(&fb[FO_T + bg*64 + j], tp);
    stepK<WIN>(c0, k0, p0); stepK<WIN>(c1, k1, p1);
  }
  so[tid] = 1.f / (1.f + __expf(-(dot0 + gbs)));
  if (a1) so[rel1] = 1.f / (1.f + __expf(-(dot1 + gbs)));
}

__global__ __launch_bounds__(256)
void k_p2b() {
  __shared__ float gss[64];
  float* fb = g_fb;
  int blk = blockIdx.x;
  int bg;
  if (blk < 864) bg = 16 + blk / 6;
  else           bg = 160 + (blk - 864) / 2;
  if (threadIdx.x < 64) gss[threadIdx.x] = fb[FO_G + bg*64 + threadIdx.x];
  __syncthreads();
  if (blk < 864) p2b_body<3, 6, 486>(blk, gss);
  else           p2b_body<5, 2, 512>(blk - 864, gss);
}

// ---------------- k_zln: wz -> z -> LayerNorm -> sigA ----------------
__global__ __launch_bounds__(64)
void k_zln(const float* __restrict__ chv_w, const float* __restrict__ chv_b,
           const float* __restrict__ chz_w, const float* __restrict__ chz_b,
           const float* __restrict__ ln_g,  const float* __restrict__ ln_b) {
  float* fb = g_fb;
  __shared__ float wzs[32]; __shared__ float zsh[64]; __shared__ float mom[2];
  int bg = blockIdx.x, tid = threadIdx.x;
  const float* t_b = fb + FO_T + bg*64;
  if (tid < 32) {
    float a = chv_b[tid];
    for (int c = 0; c < 64; ++c)
      a += chv_w[tid*64 + c] * t_b[c];
    wzs[tid] = a;
  }
  __syncthreads();
  float zv = chz_b[tid];
  for (int o = 0; o < 32; ++o)
    zv += chz_w[tid*32 + o] * wzs[o];
  zsh[tid] = zv;
  __syncthreads();
  if (tid == 0) {
    float mu = 0.f;
    for (int j = 0; j < 64; ++j) mu += zsh[j];
    mu *= (1.f/64.f);
    float m2 = 0.f;
    for (int j = 0; j < 64; ++j) { float d = zsh[j] - mu; m2 += d*d; }
    m2 *= (1.f/64.f);
    mom[0] = mu; mom[1] = rsqrtf(m2 + 1e-5f);
  }
  __syncthreads();
  float zn = (zv - mom[0]) * mom[1] * ln_g[tid] + ln_b[tid];
  fb[FO_SIGA + bg*64 + tid] = 1.f / (1.f + __expf(-zn));
}

// ---------------- k_final: coalesced gates -> extT (swizzled) -> MFMA -------
// 32-px tile, 16KB LDS. Thread t: px-octet g = t&3, channel chsel = t>>2.
// 4 rounds: win1 (ch=chsel), win3 (64+chsel), win5 (128+chsel), x (192+chsel).
// Swizzle: k' = k ^ (((px&7)^(px>>3))<<3) — transposed b16 writes conflict-free,
// b128 MFMA reads at floor, self-inverse on k bits 3..5.
template<int WIN> DEV float gate_px(int n, int s, int h, int w, int c,
                                    const float* __restrict__ fb) {
  using W = WP<WIN>;
  constexpr int SH = W::SH, KH = W::KH, K = W::K, P = W::P,
                QOFF = W::QOFF, BOFF = W::BOFF;
  const float* smap = fb + FO_SMAP + QOFF + (size_t)(n*P)*K;
  const float* sg   = fb + FO_SIGA + (size_t)(BOFF + n*P)*64;
  if constexpr (WIN == 1) {
    return 1.f + sg[c] + smap[s];
  } else {
    int phmin = (h >= KH) ? (h - KH)/SH + 1 : 0;
    int phmax = (WIN-1 < h/SH) ? WIN-1 : h/SH;
    int pwmin = (w >= KH) ? (w - KH)/SH + 1 : 0;
    int pwmax = (WIN-1 < w/SH) ? WIN-1 : w/SH;
    float gsum = 0.f; int np = 0;
    for (int ph = phmin; ph <= phmax; ++ph)
      for (int pw = pwmin; pw <= pwmax; ++pw) {
        int ki = h - ph*SH, kj = w - pw*SH;
        unsigned base0 = (unsigned)((ki*KH + kj)*P + ph*WIN + pw);
        unsigned q = base0 / (unsigned)K;
        int s0v = (int)(base0 - q*(unsigned)K);
        int cf = c*P + (int)q;
        gsum += sg[cf] + smap[(cf >> 6)*K + s0v];
        ++np;
      }
    return 1.f + gsum * (1.f / (float)np);
  }
}

template<int WIN, int SECT>
DEV void gate_round(int n, int s0, int g, int chsel,
                    const float* __restrict__ fb,
                    const bf16* __restrict__ ex, bf16* extT) {
  int pxb = g*8;
  const bf16* row = ex + ((size_t)n*192 + SECT + chsel)*25600 + s0 + pxb;
  u32x4 v = *(const u32x4*)row;
  int ch = SECT + chsel;
#pragma unroll
  for (int i = 0; i < 8; ++i) {
    int px = pxb + i; int s = s0 + px; int h = s/160; int w = s - h*160;
    float gate = gate_px<WIN>(n, s, h, w, chsel, fb);
    unsigned wd = v[i >> 1];
    unsigned short eb = (i & 1) ? (unsigned short)(wd >> 16)
                                : (unsigned short)(wd & 0xffffu);
    extT[px*256 + (ch ^ (((px&7) ^ (px>>3)) << 3))] =
        __float2bfloat16(bf2f(eb) * gate);
  }
}

__global__ __launch_bounds__(256)
void k_final(const float* __restrict__ x, float* __restrict__ out) {
  const float* fb = g_fb;
  const bf16* ex = (const bf16*)g_ex_u;
  __shared__ __align__(16) bf16 extT[32*256];   // 16 KB
  int blk = blockIdx.x; int n = blk / 800; int s0 = (blk % 800) * 32;
  int t = threadIdx.x; int g = t & 3; int chsel = t >> 2;
  gate_round<1, 0  >(n, s0, g, chsel, fb, ex, extT);
  gate_round<3, 64 >(n, s0, g, chsel, fb, ex, extT);
  gate_round<5, 128>(n, s0, g, chsel, fb, ex, extT);
  { // x passthrough: ch 192+chsel
    int pxb = g*8;
    const float* xr = x + (size_t)(n*64 + chsel)*25600 + s0 + pxb;
    f32x4 a = *(const f32x4*)xr;
    f32x4 b = *(const f32x4*)(xr + 4);
    int ch = 192 + chsel;
#pragma unroll
    for (int i = 0; i < 8; ++i) {
      float v = (i < 4) ? a[i] : b[i-4];
      int px = pxb + i;
      extT[px*256 + (ch ^ (((px&7) ^ (px>>3)) << 3))] = __float2bfloat16(v);
    }
  }
  __syncthreads();

  // ---- MFMA: out[o][px] = sum_k W[k][o] * extT[px][k], K=256, 32 px ----
  int wv = t >> 6; int l = t & 63; int lx = l & 15; int g8 = l >> 4;
  const u32x4* wfA = (const u32x4*)(fb + FO_WFRAG);
  u32x4 af[8];
#pragma unroll
  for (int ks = 0; ks < 8; ++ks) af[ks] = wfA[(wv*8 + ks)*64 + l];
  f32x4 acc[2];
  acc[0] = f32x4{0.f,0.f,0.f,0.f}; acc[1] = f32x4{0.f,0.f,0.f,0.f};
#pragma unroll
  for (int ks = 0; ks < 8; ++ks) {
#pragma unroll
    for (int pt = 0; pt < 2; ++pt) {
      int pxx = pt*16 + lx;
      const u32x4* bp = (const u32x4*)&extT[pxx*256 +
          ((ks*32 + g8*8) ^ (((pxx&7) ^ (pxx>>3)) << 3))];
      acc[pt] = __builtin_amdgcn_mfma_f32_16x16x32_bf16(
                  as_bf16x8(af[ks]), as_bf16x8(*bp), acc[pt], 0, 0, 0);
    }
  }
  float bia[4];
#pragma unroll
  for (int r = 0; r < 4; ++r) bia[r] = fb[FO_BCOMB + wv*16 + g8*4 + r];
#pragma unroll
  for (int pt = 0; pt < 2; ++pt) {
#pragma unroll
    for (int r = 0; r < 4; ++r)
      out[(size_t)(n*64 + wv*16 + g8*4 + r)*25600 + s0 + pt*16 + lx] =
          acc[pt][r] + bia[r];
  }
}

// ---------------- launch ----------------
extern "C" void kernel_launch(void* const* d_in, const int* in_sizes, int n_in,
                              void* d_out, int out_size, void* d_ws, size_t ws_size,
                              hipStream_t stream) {
  const float* x     = (const float*)d_in[0];
  const float* exp_w = (const float*)d_in[1];
  const float* exp_b = (const float*)d_in[2];
  const float* res_w = (const float*)d_in[3];
  const float* res_b = (const float*)d_in[4];
  const float* fus_w = (const float*)d_in[5];
  const float* fus_b = (const float*)d_in[6];
  const float* chv_w = (const float*)d_in[7];
  const float* chv_b = (const float*)d_in[8];
  const float* chq_w = (const float*)d_in[9];
  const float* chq_b = (const float*)d_in[10];
  const float* chz_w = (const float*)d_in[11];
  const float* chz_b = (const float*)d_in[12];
  const float* ln_g  = (const float*)d_in[13];
  const float* ln_b  = (const float*)d_in[14];
  const float* spv_w = (const float*)d_in[15];
  const float* spv_b = (const float*)d_in[16];
  const float* spq_w = (const float*)d_in[17];
  const float* spq_b = (const float*)d_in[18];
  float* out = (float*)d_out;

  k_prep<<<393, 256, 0, stream>>>(exp_w, exp_b, res_w, res_b, fus_w, fus_b);
  k_prep2<<<64, 256, 0, stream>>>();
  k_ex<<<6400, 256, 0, stream>>>(x);

  k_q1<<<1600, 256, 0, stream>>>(chq_w, chq_b);
  k_xm<<<1024, 256, 0, stream>>>();
  k_p1b<<<1664, 256, 0, stream>>>(chq_w, chq_b);

  k_bstats<<<560, 256, 0, stream>>>(spq_w, spq_b, spv_w, spv_b);

  k_sm1<<<1600, 256, 0, stream>>>();
  k_t1<<<1024, 256, 0, stream>>>();
  k_p2b<<<1664, 256, 0, stream>>>();

  k_zln<<<560, 64, 0, stream>>>(chv_w, chv_b, chz_w, chz_b, ln_g, ln_b);

  k_final<<<12800, 256, 0, stream>>>(x, out);
}